// Round 1
// baseline (497.247 us; speedup 1.0000x reference)
//
#include <hip/hip_runtime.h>

// NOE net: sequential scan over T-1 steps, B independent rows.
// 8 lanes per row; each lane owns 4 hidden units (2x float2 pairs) of both
// the output MLP (lay1/lay2) and the recurrent MLP (rlay1/rlay2).
// Cross-lane length-8 reductions via DPP butterfly (VALU-rate, no LDS).

typedef float v2 __attribute__((ext_vector_type(2)));

#define T_LEN 2048

__device__ __forceinline__ v2 mk2(float a, float b) {
  v2 r; r.x = a; r.y = b; return r;
}

template <int CTRL>
__device__ __forceinline__ float dpp_add(float v) {
  return v + __int_as_float(__builtin_amdgcn_update_dpp(
                 0, __float_as_int(v), CTRL, 0xF, 0xF, true));
}

// sum across each aligned 8-lane group; result in all 8 lanes
__device__ __forceinline__ float red8(float v) {
  v = dpp_add<0xB1>(v);   // quad_perm [1,0,3,2]  : xor 1
  v = dpp_add<0x4E>(v);   // quad_perm [2,3,0,1]  : xor 2
  v = dpp_add<0x141>(v);  // row_half_mirror      : xor 4 (within 8)
  return v;
}

__device__ __forceinline__ v2 sig2(v2 xin) {
  const float NLOG2E = -1.44269504088896340736f;
  float ex = __builtin_amdgcn_exp2f(xin.x * NLOG2E);
  float ey = __builtin_amdgcn_exp2f(xin.y * NLOG2E);
  v2 r;
  r.x = __builtin_amdgcn_rcpf(1.0f + ex);
  r.y = __builtin_amdgcn_rcpf(1.0f + ey);
  return r;
}

__global__ __launch_bounds__(256) void noenet_scan(
    const float* __restrict__ x,
    const float* __restrict__ l1w, const float* __restrict__ l1b,
    const float* __restrict__ l2w, const float* __restrict__ l2b,
    const float* __restrict__ r1w, const float* __restrict__ r1b,
    const float* __restrict__ r2w, const float* __restrict__ r2b,
    float* __restrict__ y, int B) {
  const int tid = blockIdx.x * blockDim.x + threadIdx.x;
  const int b = tid >> 3;
  const int g = tid & 7;
  if (b >= B) return;

  // Per-lane weights: units i0..i0+3, as pairs p=0 (i0,i0+1), p=1 (i0+2,i0+3).
  v2 zw0[2], zw1[2], zw2[2], zw3[2], zbv[2], ow[2];
  v2 rw0[2], rw1[2], rw2[2], rw3[2], rbv[2], q0[2], q1[2];
#pragma unroll
  for (int p = 0; p < 2; ++p) {
    const int i0 = g * 4 + 2 * p;
    const int i1 = i0 + 1;
    zw0[p] = mk2(l1w[i0 * 4 + 0], l1w[i1 * 4 + 0]);
    zw1[p] = mk2(l1w[i0 * 4 + 1], l1w[i1 * 4 + 1]);
    zw2[p] = mk2(l1w[i0 * 4 + 2], l1w[i1 * 4 + 2]);
    zw3[p] = mk2(l1w[i0 * 4 + 3], l1w[i1 * 4 + 3]);
    zbv[p] = mk2(l1b[i0], l1b[i1]);
    ow[p]  = mk2(l2w[i0], l2w[i1]);
    rw0[p] = mk2(r1w[i0 * 4 + 0], r1w[i1 * 4 + 0]);
    rw1[p] = mk2(r1w[i0 * 4 + 1], r1w[i1 * 4 + 1]);
    rw2[p] = mk2(r1w[i0 * 4 + 2], r1w[i1 * 4 + 2]);
    rw3[p] = mk2(r1w[i0 * 4 + 3], r1w[i1 * 4 + 3]);
    rbv[p] = mk2(r1b[i0], r1b[i1]);
    q0[p]  = mk2(r2w[0 * 32 + i0], r2w[0 * 32 + i1]);
    q1[p]  = mk2(r2w[1 * 32 + i0], r2w[1 * 32 + i1]);
  }
  const float ob  = l2b[0];
  const float hb0 = r2b[0];
  const float hb1 = r2b[1];

  const float* xb = x + (long)b * T_LEN;
  float* yb = y + (long)b * (T_LEN - 1);

  float h0 = 0.0f, h1 = 0.0f;

  auto step = [&](int t, float u0, float u1) {
    v2 oacc = mk2(0.0f, 0.0f);
    v2 p0acc = mk2(0.0f, 0.0f);
    v2 p1acc = mk2(0.0f, 0.0f);
#pragma unroll
    for (int p = 0; p < 2; ++p) {
      v2 za = zbv[p] + zw0[p] * u0 + zw1[p] * u1 + zw2[p] * h0 + zw3[p] * h1;
      v2 z = sig2(za);
      oacc += z * ow[p];
      v2 ra = rbv[p] + rw0[p] * u0 + rw1[p] * u1 + rw2[p] * h0 + rw3[p] * h1;
      v2 hz = sig2(ra);
      p0acc += hz * q0[p];
      p1acc += hz * q1[p];
    }
    float o   = red8(oacc.x + oacc.y) + ob;
    float nh0 = red8(p0acc.x + p0acc.y) + hb0;
    float nh1 = red8(p1acc.x + p1acc.y) + hb1;
    if (g == 0) yb[t] = o;
    h0 = nh0;
    h1 = nh1;
  };

  float4 cur = *reinterpret_cast<const float4*>(xb);
  for (int c = 0; c < 511; ++c) {
    float4 nxt = *reinterpret_cast<const float4*>(xb + 4 * c + 4);
    const int t = 4 * c;
    step(t + 0, cur.x, cur.y);
    step(t + 1, cur.y, cur.z);
    step(t + 2, cur.z, cur.w);
    step(t + 3, cur.w, nxt.x);
    cur = nxt;
  }
  // tail: cur = x[2044..2047] -> steps 2044, 2045, 2046
  step(2044, cur.x, cur.y);
  step(2045, cur.y, cur.z);
  step(2046, cur.z, cur.w);
}

extern "C" void kernel_launch(void* const* d_in, const int* in_sizes, int n_in,
                              void* d_out, int out_size, void* d_ws, size_t ws_size,
                              hipStream_t stream) {
  const float* x   = (const float*)d_in[0];
  const float* l1w = (const float*)d_in[1];
  const float* l1b = (const float*)d_in[2];
  const float* l2w = (const float*)d_in[3];
  const float* l2b = (const float*)d_in[4];
  const float* r1w = (const float*)d_in[5];
  const float* r1b = (const float*)d_in[6];
  const float* r2w = (const float*)d_in[7];
  const float* r2b = (const float*)d_in[8];
  float* y = (float*)d_out;

  const int B = in_sizes[0] / T_LEN;  // 8192
  const int threads = B * 8;          // 8 lanes per batch row
  const int block = 256;
  const int grid = (threads + block - 1) / block;

  noenet_scan<<<grid, block, 0, stream>>>(x, l1w, l1b, l2w, l2b,
                                          r1w, r1b, r2w, r2b, y, B);
}